// Round 9
// baseline (117.088 us; speedup 1.0000x reference)
//
#include <hip/hip_runtime.h>

#define IGNORE_LABEL (-100)

typedef float f32x4 __attribute__((ext_vector_type(4)));

#define NS    8        // voxel slices == XCDs (block bid%8 -> XCD bid%8)
#define VCAP  80000    // per-slice list capacity (expect ~61.4K)
#define ICAP  160000   // invalid list capacity (expect ~122.9K)

// d_out: [P*128 proj | P idx passthrough | V counts]  (flat f32)
// d_ws : [q8 table V*128 (12.8MB) | scales V | cursor 64 | listP | listV]
//
// Model (R4/R7/R8 evidence): gather is DRAM row-activation-bound (~491K random
// row touches ~= 110us). Fix = serve gathers from CU-side L2: int8 slice =
// 1.6MB << 4MB L2/XCD, and proj stores use sc0/sc1/nt (system-scope
// write-through, no L2 allocate) so the 317MB write stream can't evict it.

__device__ __forceinline__ void store_nt(f32x4 v, f32x4* addr) {
    asm volatile("global_store_dwordx4 %0, %1, off sc0 sc1 nt"
                 :: "v"(addr), "v"(v) : "memory");
}

__device__ __forceinline__ f32x4 dec8(unsigned int u, float sc) {
    f32x4 r;
    r.x = (float)(int)(signed char)(u & 0xffu);
    r.y = (float)(int)(signed char)((u >> 8) & 0xffu);
    r.z = (float)(int)(signed char)((u >> 16) & 0xffu);
    r.w = (float)(int)(signed char)(u >> 24);
    r.x *= sc; r.y *= sc; r.z *= sc; r.w *= sc;
    return r;
}

// ---- prep: int8 quantize (per-row scale) + hist/lists + passthrough + counts ----
__global__ __launch_bounds__(256) void k_prep(
        const f32x4* __restrict__ feat4,   // [V*32]
        const int*   __restrict__ idx,     // [P]
        unsigned int* __restrict__ q8,     // [V*32] packed int8x4
        float*       __restrict__ scales,  // [V]
        float*       __restrict__ idx_out, // [P]
        float*       __restrict__ counts,  // [V]
        int*         __restrict__ cursor,  // [>=NS+1]
        int*         __restrict__ listP,
        int*         __restrict__ listV,
        int V, int P, int sliceW) {
    // --- part A: quantize rows (32 lanes per row) ---
    const int gtid = blockIdx.x * 256 + threadIdx.x;
    const int l    = threadIdx.x & 31;
    const int grp  = gtid >> 5;
    const int ngrp = (gridDim.x * 256) >> 5;
    for (int r = grp; r < V; r += ngrp) {
        const f32x4 x = feat4[(size_t)r * 32 + l];
        float m = fmaxf(fmaxf(fabsf(x.x), fabsf(x.y)), fmaxf(fabsf(x.z), fabsf(x.w)));
        #pragma unroll
        for (int d = 1; d < 32; d <<= 1) m = fmaxf(m, __shfl_xor(m, d, 32));
        m = fmaxf(m, 1e-20f);
        const float inv = 127.0f / m;
        const int a = (int)rintf(x.x * inv);
        const int b = (int)rintf(x.y * inv);
        const int c = (int)rintf(x.z * inv);
        const int d4 = (int)rintf(x.w * inv);
        q8[(size_t)r * 32 + l] = (unsigned int)(a & 255) | ((unsigned int)(b & 255) << 8)
                               | ((unsigned int)(c & 255) << 16) | ((unsigned int)(d4 & 255) << 24);
        if (l == 0) scales[r] = m / 127.0f;
    }

    // --- part B: 4 pixels/thread: passthrough + counts + slice lists ---
    __shared__ int hcnt[NS + 1], hbase[NS + 1], hoff[NS + 1];
    const int t = threadIdx.x;
    if (t <= NS) { hcnt[t] = 0; hoff[t] = 0; }
    __syncthreads();

    const int p0 = gtid * 4;
    int v[4], bin[4]; bool have = false;
    if (p0 + 3 < P) {
        const int4 q = *(const int4*)(idx + p0);
        v[0] = q.x; v[1] = q.y; v[2] = q.z; v[3] = q.w;
        float4 f; f.x = (float)q.x; f.y = (float)q.y; f.z = (float)q.z; f.w = (float)q.w;
        *(float4*)(idx_out + p0) = f;
        have = true;
        #pragma unroll
        for (int k = 0; k < 4; ++k) {
            if (v[k] != IGNORE_LABEL) {
                int s = v[k] / sliceW; s = s > NS - 1 ? NS - 1 : s;
                bin[k] = s;
                atomicAdd(&counts[v[k]], 1.0f);
            } else bin[k] = NS;
            atomicAdd(&hcnt[bin[k]], 1);
        }
    }
    __syncthreads();
    if (t <= NS) hbase[t] = atomicAdd(&cursor[t], hcnt[t]);
    __syncthreads();
    if (have) {
        #pragma unroll
        for (int k = 0; k < 4; ++k) {
            const int b = bin[k];
            const int pos = hbase[b] + atomicAdd(&hoff[b], 1);
            if (b < NS) {
                if (pos < VCAP) { listP[b * VCAP + pos] = p0 + k; listV[b * VCAP + pos] = v[k]; }
            } else {
                if (pos < ICAP) listP[NS * VCAP + pos] = p0 + k;
            }
        }
    }
}

// ---- gather: cohort bid%8 serves slice s from its XCD's L2 ----
__global__ __launch_bounds__(256) void k_gather(
        const unsigned int* __restrict__ q8,     // [V*32]
        const float*        __restrict__ scales, // [V]
        const int*          __restrict__ cursor,
        const int*          __restrict__ listP,
        const int*          __restrict__ listV,
        f32x4*              __restrict__ proj) { // [P*32]
    const int s    = blockIdx.x & (NS - 1);
    const int lane = threadIdx.x & 31;
    const int gid  = (blockIdx.x >> 3) * 8 + (threadIdx.x >> 5);  // 0..2047
    const int base = s * VCAP;
    int n = cursor[s]; n = n > VCAP ? VCAP : n;

    int i = gid;
    for (; i + 2048 < n; i += 4096) {
        const int pA = listP[base + i],        vA = listV[base + i];
        const int pB = listP[base + i + 2048], vB = listV[base + i + 2048];
        const unsigned int qA = q8[(size_t)vA * 32 + lane];   // L2-resident slice
        const unsigned int qB = q8[(size_t)vB * 32 + lane];
        const float sA = scales[vA], sB = scales[vB];
        store_nt(dec8(qA, sA), &proj[(size_t)pA * 32 + lane]);
        store_nt(dec8(qB, sB), &proj[(size_t)pB * 32 + lane]);
    }
    for (; i < n; i += 2048) {
        const int p = listP[base + i], vv = listV[base + i];
        store_nt(dec8(q8[(size_t)vv * 32 + lane], scales[vv]),
                 &proj[(size_t)p * 32 + lane]);
    }

    // zero rows for misses (all 16384 groups stripe the invalid list)
    int ninv = cursor[NS]; ninv = ninv > ICAP ? ICAP : ninv;
    const int G = blockIdx.x * 8 + (threadIdx.x >> 5);
    const f32x4 z = (f32x4)(0.f);
    for (int j = G; j < ninv; j += 16384) {
        const int p = listP[NS * VCAP + j];
        store_nt(z, &proj[(size_t)p * 32 + lane]);
    }
}

// ---- fallback: round-4 kernel if ws too small ----
__global__ void k_fallback(const f32x4* __restrict__ feat,
                           const int* __restrict__ idx,
                           f32x4* __restrict__ proj,
                           float* __restrict__ idx_out,
                           float* __restrict__ counts, int P) {
    const int tid  = blockIdx.x * blockDim.x + threadIdx.x;
    const int lane = tid & 31;
    const int grp0 = tid >> 5;
    const int ngrp = (gridDim.x * blockDim.x) >> 5;
    for (int p = grp0; p < P; p += ngrp) {
        const int v = idx[p];
        const bool valid = (v != IGNORE_LABEL);
        const int s = valid ? v : 0;
        f32x4 a = feat[(size_t)s * 32 + lane];
        if (!valid) a = (f32x4)(0.f);
        proj[(size_t)p * 32 + lane] = a;
        if (lane == 0) {
            idx_out[p] = (float)v;
            if (valid) atomicAdd(&counts[v], 1.0f);
        }
    }
}

extern "C" void kernel_launch(void* const* d_in, const int* in_sizes, int n_in,
                              void* d_out, int out_size, void* d_ws, size_t ws_size,
                              hipStream_t stream) {
    const float* feat = (const float*)d_in[0];   // [V,128] f32
    const int*   idx  = (const int*)d_in[1];     // [P] i32

    const int D = 128;
    const int V = in_sizes[0] / D;     // 100000
    const int P = in_sizes[1];         // 614400

    float* out     = (float*)d_out;
    float* idx_out = out + (size_t)P * D;
    float* counts  = idx_out + P;

    (void)hipMemsetAsync(counts, 0, (size_t)V * sizeof(float), stream);

    const size_t q8Bytes = (size_t)V * D;                       // 12.8 MB
    const size_t need = q8Bytes + (size_t)V * 4 + 256
                      + (size_t)(NS * VCAP + ICAP) * 4
                      + (size_t)(NS * VCAP) * 4;                // ~19 MB
    if (ws_size < need) {
        k_fallback<<<2048, 256, 0, stream>>>((const f32x4*)feat, idx,
                                             (f32x4*)out, idx_out, counts, P);
        return;
    }

    unsigned int* q8     = (unsigned int*)d_ws;
    float*        scales = (float*)((char*)d_ws + q8Bytes);
    int*          cursor = (int*)(scales + V);
    int*          listP  = cursor + 64;
    int*          listV  = listP + (NS * VCAP + ICAP);
    const int sliceW = (V + NS - 1) / NS;   // 12500

    (void)hipMemsetAsync(cursor, 0, 64 * sizeof(int), stream);

    k_prep<<<2048, 256, 0, stream>>>((const f32x4*)feat, idx, q8, scales,
                                     idx_out, counts, cursor, listP, listV,
                                     V, P, sliceW);
    k_gather<<<2048, 256, 0, stream>>>(q8, scales, cursor, listP, listV,
                                       (f32x4*)out);
}

// Round 10
// 110.098 us; speedup vs baseline: 1.0635x; 1.0635x over previous
//
#include <hip/hip_runtime.h>

#define IGNORE_LABEL (-100)

typedef float f32x4 __attribute__((ext_vector_type(4)));

// d_out layout (flat float32): [P*128 proj | P idx passthrough | V counts]
//
// FINAL (round-4 kernel, 109.4 us, absmax 0). Pixel-major gather:
// sequential 317 MB write stream + ~491K random 512 B reads.
//
// Why this is the roofline (rounds 5-9 evidence):
//  - Not latency-bound: 2x MLP unroll changed nothing (R4 == R1).
//  - Not read-byte-bound: bf16 (R7) and int8 (R9) gather payloads changed
//    nothing -> bound by random-touch count, not bytes.
//  - Restructuring (XCD-sliced L2-resident table R5/R8/R9, counting sort R6)
//    converts random reads into random 512 B writes (~614K touches at
//    ~3.3 TB/s effective) + prep overhead -> all landed 116-156 us.
//  - Conservation law: the pixel<->voxel permutation pays random DRAM
//    touches on one side; pixel-major (reads random) is the cheaper side.
//  - Efficiency: 571 MB fabric traffic / 109.4 us = 5.2 TB/s = ~80% of the
//    6.9 TB/s pure-stream write ceiling measured on this chip's fill kernels.
__global__ void RaycastFeatures_42597485641917_kernel(
        const f32x4* __restrict__ feat,   // [V][32] f32x4 view of [V][128] f32
        const int*   __restrict__ idx,    // [P]
        f32x4*       __restrict__ proj,   // [P][32] f32x4 view
        float*       __restrict__ idx_out,// [P]
        float*       __restrict__ counts, // [V], pre-zeroed
        int P) {
    const int tid  = blockIdx.x * blockDim.x + threadIdx.x;
    const int lane = tid & 31;
    const int grp0 = tid >> 5;
    const int ngrp = (gridDim.x * blockDim.x) >> 5;

    int p = grp0;
    for (; p + ngrp < P; p += 2 * ngrp) {
        const int p0 = p, p1 = p + ngrp;
        const int v0 = idx[p0];
        const int v1 = idx[p1];
        const bool valid0 = (v0 != IGNORE_LABEL);
        const bool valid1 = (v1 != IGNORE_LABEL);
        const int s0 = valid0 ? v0 : 0;
        const int s1 = valid1 ? v1 : 0;

        // issue both gathers before any store
        f32x4 a = feat[(size_t)s0 * 32 + lane];
        f32x4 b = feat[(size_t)s1 * 32 + lane];
        if (!valid0) a = (f32x4)(0.f);
        if (!valid1) b = (f32x4)(0.f);

        proj[(size_t)p0 * 32 + lane] = a;
        proj[(size_t)p1 * 32 + lane] = b;

        if (lane == 0) {
            idx_out[p0] = (float)v0;
            idx_out[p1] = (float)v1;
            if (valid0) atomicAdd(&counts[v0], 1.0f);
            if (valid1) atomicAdd(&counts[v1], 1.0f);
        }
    }
    for (; p < P; p += ngrp) {
        const int v = idx[p];
        const bool valid = (v != IGNORE_LABEL);
        const int s = valid ? v : 0;
        f32x4 a = feat[(size_t)s * 32 + lane];
        if (!valid) a = (f32x4)(0.f);
        proj[(size_t)p * 32 + lane] = a;
        if (lane == 0) {
            idx_out[p] = (float)v;
            if (valid) atomicAdd(&counts[v], 1.0f);
        }
    }
}

extern "C" void kernel_launch(void* const* d_in, const int* in_sizes, int n_in,
                              void* d_out, int out_size, void* d_ws, size_t ws_size,
                              hipStream_t stream) {
    const float* feat = (const float*)d_in[0];   // [V,128] f32
    const int*   idx  = (const int*)d_in[1];     // [P] i32

    const int D = 128;
    const int V = in_sizes[0] / D;     // 100000
    const int P = in_sizes[1];         // 614400

    float* out     = (float*)d_out;
    f32x4* proj    = (f32x4*)out;
    float* idx_out = out + (size_t)P * D;
    float* counts  = idx_out + P;

    // Counts must start at 0 every replay (harness poisons once, never again).
    (void)hipMemsetAsync(counts, 0, (size_t)V * sizeof(float), stream);

    const int block = 256;             // 4 waves/block
    const int grid  = 2048;            // 8192 waves = 32/CU, full occupancy
    RaycastFeatures_42597485641917_kernel<<<grid, block, 0, stream>>>(
        (const f32x4*)feat, idx, proj, idx_out, counts, P);
}